// Round 1
// baseline (1520.082 us; speedup 1.0000x reference)
//
#include <hip/hip_runtime.h>
#include <hip/hip_bf16.h>
#include <math.h>

// Problem constants (B=4, T=1024, H=1024, V=32000)
constexpr int kH    = 1024;
constexpr int kV    = 32000;
constexpr int kTok  = 4096;   // B*T
constexpr int BM    = 128;
constexpr int BN    = 128;
constexpr int BK    = 32;
constexpr int NVT   = kV / BN;   // 250 vocab tiles
constexpr int NMT   = kTok / BM; // 32 token tiles

typedef _Float16 f16x8 __attribute__((ext_vector_type(8)));
typedef _Float16 f16x4 __attribute__((ext_vector_type(4)));
typedef float    f32x4 __attribute__((ext_vector_type(4)));

// GEMM over (tokens x vocab-tile), fused per-row (max, sum-exp) partial epilogue.
// partials[vtile * kTok + token] = (rowmax, sum exp(logit - rowmax)) over 128 vocab cols.
__global__ __launch_bounds__(256) void lse_gemm_kernel(
    const float* __restrict__ X, const float* __restrict__ W,
    float2* __restrict__ partials)
{
  __shared__ _Float16 As[BM * BK];
  __shared__ _Float16 Bs[BN * BK];
  __shared__ float redm[2][BM];
  __shared__ float reds[2][BM];

  const int tid    = threadIdx.x;
  const int m_base = blockIdx.x * BM;
  const int v_base = blockIdx.y * BN;

  const int wave = tid >> 6;
  const int lane = tid & 63;
  const int quad = lane >> 4;
  const int lc   = lane & 15;
  const int rb   = (wave & 1) * 64;   // row (token) sub-block of this wave
  const int cb   = (wave >> 1) * 64;  // col (vocab) sub-block of this wave

  f32x4 acc[4][4];
#pragma unroll
  for (int i = 0; i < 4; ++i)
#pragma unroll
    for (int j = 0; j < 4; ++j) acc[i][j] = (f32x4){0.f, 0.f, 0.f, 0.f};

  for (int k0 = 0; k0 < kH; k0 += BK) {
    // Stage A (tokens) and B (vocab rows of W) tiles: fp32 load -> f16 LDS.
    // 128x32 fp32 = 1024 float4 loads, 256 threads x 4 each.
#pragma unroll
    for (int l = 0; l < 4; ++l) {
      int f   = tid + l * 256;
      int row = f >> 3;
      int c4  = (f & 7) << 2;
      float4 va = *(const float4*)&X[(size_t)(m_base + row) * kH + k0 + c4];
      f16x4 pa = { (_Float16)va.x, (_Float16)va.y, (_Float16)va.z, (_Float16)va.w };
      *(f16x4*)&As[row * BK + c4] = pa;
      float4 vb = *(const float4*)&W[(size_t)(v_base + row) * kH + k0 + c4];
      f16x4 pb = { (_Float16)vb.x, (_Float16)vb.y, (_Float16)vb.z, (_Float16)vb.w };
      *(f16x4*)&Bs[row * BK + c4] = pb;
    }
    __syncthreads();

    // A fragment: lane holds A[m = lane&15][k = quad*8 + j], contiguous 8 f16.
    f16x8 af[4], bfr[4];
#pragma unroll
    for (int i = 0; i < 4; ++i)
      af[i] = *(f16x8*)&As[(rb + i * 16 + lc) * BK + quad * 8];
#pragma unroll
    for (int j = 0; j < 4; ++j)
      bfr[j] = *(f16x8*)&Bs[(cb + j * 16 + lc) * BK + quad * 8];

#pragma unroll
    for (int i = 0; i < 4; ++i)
#pragma unroll
      for (int j = 0; j < 4; ++j)
        acc[i][j] = __builtin_amdgcn_mfma_f32_16x16x32_f16(af[i], bfr[j], acc[i][j], 0, 0, 0);
    __syncthreads();
  }

  // Epilogue: per-token (row) max and sum-exp over the block's 128 columns.
  // C/D layout: row = quad*4 + reg, col = lane&15 (within each 16x16 subtile).
#pragma unroll
  for (int i = 0; i < 4; ++i) {
#pragma unroll
    for (int r = 0; r < 4; ++r) {
      int row_local = rb + i * 16 + quad * 4 + r;
      float v0 = acc[i][0][r], v1 = acc[i][1][r], v2 = acc[i][2][r], v3 = acc[i][3][r];
      float m = fmaxf(fmaxf(v0, v1), fmaxf(v2, v3));
#pragma unroll
      for (int st = 1; st < 16; st <<= 1) m = fmaxf(m, __shfl_xor(m, st, 16));
      float s = __expf(v0 - m) + __expf(v1 - m) + __expf(v2 - m) + __expf(v3 - m);
#pragma unroll
      for (int st = 1; st < 16; st <<= 1) s += __shfl_xor(s, st, 16);
      if (lc == 0) { redm[wave >> 1][row_local] = m; reds[wave >> 1][row_local] = s; }
    }
  }
  __syncthreads();
  if (tid < BM) {
    float m1 = redm[0][tid], s1 = reds[0][tid];
    float m2 = redm[1][tid], s2 = reds[1][tid];
    float M = fmaxf(m1, m2);
    float S = s1 * __expf(m1 - M) + s2 * __expf(m2 - M);
    partials[(size_t)blockIdx.y * kTok + m_base + tid] = make_float2(M, S);
  }
}

// Exact fp32 selected-logit: one wave per token, both models via blockIdx.y.
__global__ __launch_bounds__(256) void sel_kernel(
    const float* __restrict__ X0, const float* __restrict__ W0,
    const float* __restrict__ X1, const float* __restrict__ W1,
    const int* __restrict__ ids, float* __restrict__ sel0, float* __restrict__ sel1)
{
  const int model = blockIdx.y;
  const float* X = model ? X1 : X0;
  const float* W = model ? W1 : W0;
  float* out = model ? sel1 : sel0;
  const int wave = threadIdx.x >> 6, lane = threadIdx.x & 63;
  const int t  = blockIdx.x * 4 + wave;
  const int id = ids[t];
  const float* xr = X + (size_t)t * kH;
  const float* wr = W + (size_t)id * kH;
  float s = 0.f;
#pragma unroll
  for (int r = 0; r < 4; ++r) {
    int idx = r * 256 + lane * 4;
    float4 a = *(const float4*)&xr[idx];
    float4 b = *(const float4*)&wr[idx];
    s += a.x * b.x + a.y * b.y + a.z * b.z + a.w * b.w;
  }
#pragma unroll
  for (int st = 32; st; st >>= 1) s += __shfl_xor(s, st, 64);
  if (lane == 0) out[t] = s;
}

// Per-token: combine 250 partials per model -> lse; GRPO per-token loss; reduce.
__global__ __launch_bounds__(256) void finalize_kernel(
    const float2* __restrict__ P0, const float2* __restrict__ P1,
    const float* __restrict__ sel0, const float* __restrict__ sel1,
    const float* __restrict__ adv, const int* __restrict__ mask,
    float* __restrict__ accum)
{
  const int t = blockIdx.x * 256 + threadIdx.x;  // 0..4095
  float M0 = -INFINITY, S0 = 0.f, M1 = -INFINITY, S1 = 0.f;
  for (int i = 0; i < NVT; ++i) {
    float2 p = P0[(size_t)i * kTok + t];
    if (p.x > M0) { S0 = S0 * __expf(M0 - p.x) + p.y; M0 = p.x; }
    else          { S0 += p.y * __expf(p.x - M0); }
  }
  for (int i = 0; i < NVT; ++i) {
    float2 p = P1[(size_t)i * kTok + t];
    if (p.x > M1) { S1 = S1 * __expf(M1 - p.x) + p.y; M1 = p.x; }
    else          { S1 += p.y * __expf(p.x - M1); }
  }
  float lse0  = M0 + logf(S0);
  float lse1  = M1 + logf(S1);
  float logp  = sel0[t] - lse0;   // policy
  float rlogp = sel1[t] - lse1;   // reference (stop-grad)
  float d  = rlogp - logp;
  float kl = __expf(d) - d - 1.f;
  // coef_1 = exp(logps - stop_grad(logps)) == 1, clip(1) == 1 -> loss = -adv + beta*kl
  float a  = adv[t >> 10];        // T = 1024
  float mv = (float)mask[t];
  float loss = (-a + 0.1f * kl) * mv;

#pragma unroll
  for (int st = 32; st; st >>= 1) {
    loss += __shfl_xor(loss, st, 64);
    mv   += __shfl_xor(mv, st, 64);
  }
  __shared__ float lsum[4], msum[4];
  const int wave = threadIdx.x >> 6, lane = threadIdx.x & 63;
  if (lane == 0) { lsum[wave] = loss; msum[wave] = mv; }
  __syncthreads();
  if (threadIdx.x == 0) {
    atomicAdd(&accum[0], lsum[0] + lsum[1] + lsum[2] + lsum[3]);
    atomicAdd(&accum[1], msum[0] + msum[1] + msum[2] + msum[3]);
  }
}

__global__ void scalar_kernel(const float* __restrict__ accum, float* __restrict__ out)
{
  out[0] = accum[0] / fmaxf(accum[1], 1.f);
}

extern "C" void kernel_launch(void* const* d_in, const int* in_sizes, int n_in,
                              void* d_out, int out_size, void* d_ws, size_t ws_size,
                              hipStream_t stream)
{
  const float* x    = (const float*)d_in[0];
  const float* w    = (const float*)d_in[1];
  const float* rx   = (const float*)d_in[2];
  const float* rw   = (const float*)d_in[3];
  const float* adv  = (const float*)d_in[4];
  const int*   ids  = (const int*)d_in[5];
  const int*   mask = (const int*)d_in[6];
  float* out = (float*)d_out;

  char* ws = (char*)d_ws;
  const size_t P_bytes = (size_t)NVT * kTok * sizeof(float2);  // 8,192,000 B
  float2* P0   = (float2*)ws;
  float2* P1   = (float2*)(ws + P_bytes);
  float*  sel0 = (float*)(ws + 2 * P_bytes);
  float*  sel1 = sel0 + kTok;
  float*  accum = sel1 + kTok;   // 2 floats; total ws use ~16.4 MB

  hipMemsetAsync(accum, 0, 2 * sizeof(float), stream);

  sel_kernel<<<dim3(kTok / 4, 2), 256, 0, stream>>>(x, w, rx, rw, ids, sel0, sel1);
  lse_gemm_kernel<<<dim3(NMT, NVT), 256, 0, stream>>>(x,  w,  P0);
  lse_gemm_kernel<<<dim3(NMT, NVT), 256, 0, stream>>>(rx, rw, P1);
  finalize_kernel<<<kTok / 256, 256, 0, stream>>>(P0, P1, sel0, sel1, adv, mask, accum);
  scalar_kernel<<<1, 1, 0, stream>>>(accum, out);
}

// Round 2
// 1254.605 us; speedup vs baseline: 1.2116x; 1.2116x over previous
//
#include <hip/hip_runtime.h>
#include <hip/hip_bf16.h>
#include <math.h>

// Problem constants (B=4, T=1024, H=1024, V=32000)
constexpr int kH   = 1024;
constexpr int kV   = 32000;
constexpr int kTok = 4096;    // B*T
constexpr int BM   = 128;
constexpr int BN   = 128;
constexpr int BK   = 64;      // f16 elements per K-step
constexpr int NVT  = kV / BN;    // 250
constexpr int NMT  = kTok / BM;  // 32

typedef _Float16 f16x8 __attribute__((ext_vector_type(8)));
typedef float    f32x4 __attribute__((ext_vector_type(4)));

typedef __attribute__((address_space(1))) const void gvoid_t;
typedef __attribute__((address_space(3))) void lvoid_t;

// fp32 -> f16 with XOR-swizzled 16B blocks: within each 64-elem K-chunk,
// logical block c of row r lands at physical block c ^ (r & 7). This makes the
// GEMM's global_load_lds staging linear while its ds_read_b128 fragment reads
// spread over 8 bank groups (2-way only -> free).
__global__ __launch_bounds__(256) void convert_kernel(
    const float* __restrict__ src, _Float16* __restrict__ dst)
{
  int idx = blockIdx.x * 256 + threadIdx.x;   // one 8-elem block per thread
  int row = idx >> 7;                          // kH/8 = 128 blocks per row
  int blk = idx & 127;
  int chunk = blk >> 3;                        // 64-elem chunk (16 per row)
  int c = blk & 7;
  int p = c ^ (row & 7);
  const float* s = src + ((size_t)row << 10) + (blk << 3);
  float4 v0 = *(const float4*)s;
  float4 v1 = *(const float4*)(s + 4);
  f16x8 o = { (_Float16)v0.x, (_Float16)v0.y, (_Float16)v0.z, (_Float16)v0.w,
              (_Float16)v1.x, (_Float16)v1.y, (_Float16)v1.z, (_Float16)v1.w };
  *(f16x8*)&dst[((size_t)row << 10) + (chunk << 6) + (p << 3)] = o;
}

// Fused GEMM + per-row (max, sum-exp) partials over each 128-col vocab tile.
// blockIdx.z selects model (policy / reference).
__global__ __launch_bounds__(256) void lse_gemm_kernel(
    const _Float16* __restrict__ X0, const _Float16* __restrict__ W0,
    const _Float16* __restrict__ X1, const _Float16* __restrict__ W1,
    float2* __restrict__ P0, float2* __restrict__ P1)
{
  __shared__ _Float16 As[BM * BK];   // 16 KB
  __shared__ _Float16 Bs[BN * BK];   // 16 KB

  const _Float16* Xp = blockIdx.z ? X1 : X0;
  const _Float16* Wp = blockIdx.z ? W1 : W0;
  float2* Pp = blockIdx.z ? P1 : P0;

  const int tid    = threadIdx.x;
  const int m_base = blockIdx.x * BM;
  const int v_base = blockIdx.y * BN;

  const int wave = tid >> 6;
  const int lane = tid & 63;
  const int quad = lane >> 4;
  const int lc   = lane & 15;
  const int rb   = (wave & 1) * 64;   // token sub-block of this wave
  const int cb   = (wave >> 1) * 64;  // vocab sub-block of this wave

  // Staging sources: lane covers (8-row group r8 = wave*4+l), row = r8*8 + lane/8,
  // 16B physical block sp = lane%8. Destination LDS = group base + lane*16 (HW).
  const int srow = lane >> 3;
  const int sp   = lane & 7;
  const _Float16* gA[4];
  const _Float16* gB[4];
#pragma unroll
  for (int l = 0; l < 4; ++l) {
    int r8  = wave * 4 + l;
    int row = r8 * 8 + srow;
    gA[l] = Xp + (size_t)(m_base + row) * kH + sp * 8;
    gB[l] = Wp + (size_t)(v_base + row) * kH + sp * 8;
  }

  // Fragment LDS offsets (f16 units), constant across K-steps.
  int offA0[4], offA1[4], offB0[4], offB1[4];
#pragma unroll
  for (int i = 0; i < 4; ++i) {
    int ra = rb + i * 16 + lc;
    offA0[i] = ra * BK + ((quad ^ (ra & 7)) << 3);
    offA1[i] = ra * BK + (((quad + 4) ^ (ra & 7)) << 3);
    int rbm = cb + i * 16 + lc;
    offB0[i] = rbm * BK + ((quad ^ (rbm & 7)) << 3);
    offB1[i] = rbm * BK + (((quad + 4) ^ (rbm & 7)) << 3);
  }

  f32x4 acc[4][4];
#pragma unroll
  for (int i = 0; i < 4; ++i)
#pragma unroll
    for (int j = 0; j < 4; ++j) acc[i][j] = (f32x4){0.f, 0.f, 0.f, 0.f};

  for (int ks = 0; ks < kH / BK; ++ks) {
#pragma unroll
    for (int l = 0; l < 4; ++l) {
      int r8 = wave * 4 + l;
      __builtin_amdgcn_global_load_lds((gvoid_t*)gA[l], (lvoid_t*)&As[r8 * 512], 16, 0, 0);
      __builtin_amdgcn_global_load_lds((gvoid_t*)gB[l], (lvoid_t*)&Bs[r8 * 512], 16, 0, 0);
      gA[l] += BK;
      gB[l] += BK;
    }
    __syncthreads();

    f16x8 a0[4], a1[4], b0[4], b1[4];
#pragma unroll
    for (int i = 0; i < 4; ++i) {
      a0[i] = *(const f16x8*)&As[offA0[i]];
      a1[i] = *(const f16x8*)&As[offA1[i]];
    }
#pragma unroll
    for (int j = 0; j < 4; ++j) {
      b0[j] = *(const f16x8*)&Bs[offB0[j]];
      b1[j] = *(const f16x8*)&Bs[offB1[j]];
    }
#pragma unroll
    for (int i = 0; i < 4; ++i)
#pragma unroll
      for (int j = 0; j < 4; ++j) {
        acc[i][j] = __builtin_amdgcn_mfma_f32_16x16x32_f16(a0[i], b0[j], acc[i][j], 0, 0, 0);
        acc[i][j] = __builtin_amdgcn_mfma_f32_16x16x32_f16(a1[i], b1[j], acc[i][j], 0, 0, 0);
      }
    __syncthreads();
  }

  // Epilogue: per-token max & sum-exp over this block's 128 vocab cols.
  // C/D layout: row = quad*4 + reg, col = lane&15 within each 16x16 subtile.
  float* redm = (float*)As;        // reuse LDS: 2 planes x 128 floats
  float* reds = redm + 256;
#pragma unroll
  for (int i = 0; i < 4; ++i) {
#pragma unroll
    for (int r = 0; r < 4; ++r) {
      int row_local = rb + i * 16 + quad * 4 + r;
      float v0 = acc[i][0][r], v1 = acc[i][1][r], v2 = acc[i][2][r], v3 = acc[i][3][r];
      float m = fmaxf(fmaxf(v0, v1), fmaxf(v2, v3));
#pragma unroll
      for (int st = 1; st < 16; st <<= 1) m = fmaxf(m, __shfl_xor(m, st, 16));
      float s = __expf(v0 - m) + __expf(v1 - m) + __expf(v2 - m) + __expf(v3 - m);
#pragma unroll
      for (int st = 1; st < 16; st <<= 1) s += __shfl_xor(s, st, 16);
      if (lc == 0) { redm[(wave >> 1) * 128 + row_local] = m; reds[(wave >> 1) * 128 + row_local] = s; }
    }
  }
  __syncthreads();
  if (tid < BM) {
    float m1 = redm[tid], s1 = reds[tid];
    float m2 = redm[128 + tid], s2 = reds[128 + tid];
    float M = fmaxf(m1, m2);
    float S = s1 * __expf(m1 - M) + s2 * __expf(m2 - M);
    Pp[(size_t)blockIdx.y * kTok + m_base + tid] = make_float2(M, S);
  }
}

// Exact fp32 selected-logit from the ORIGINAL fp32 inputs.
__global__ __launch_bounds__(256) void sel_kernel(
    const float* __restrict__ X0, const float* __restrict__ W0,
    const float* __restrict__ X1, const float* __restrict__ W1,
    const int* __restrict__ ids, float* __restrict__ sel0, float* __restrict__ sel1)
{
  const int model = blockIdx.y;
  const float* X = model ? X1 : X0;
  const float* W = model ? W1 : W0;
  float* out = model ? sel1 : sel0;
  const int wave = threadIdx.x >> 6, lane = threadIdx.x & 63;
  const int t  = blockIdx.x * 4 + wave;
  const int id = ids[t];
  const float* xr = X + (size_t)t * kH;
  const float* wr = W + (size_t)id * kH;
  float s = 0.f;
#pragma unroll
  for (int r = 0; r < 4; ++r) {
    int idx = r * 256 + lane * 4;
    float4 a = *(const float4*)&xr[idx];
    float4 b = *(const float4*)&wr[idx];
    s += a.x * b.x + a.y * b.y + a.z * b.z + a.w * b.w;
  }
#pragma unroll
  for (int st = 32; st; st >>= 1) s += __shfl_xor(s, st, 64);
  if (lane == 0) out[t] = s;
}

// Combine 250 partials/model -> lse; GRPO loss; reduce.
__global__ __launch_bounds__(256) void finalize_kernel(
    const float2* __restrict__ P0, const float2* __restrict__ P1,
    const float* __restrict__ sel0, const float* __restrict__ sel1,
    const float* __restrict__ adv, const int* __restrict__ mask,
    float* __restrict__ accum)
{
  const int t = blockIdx.x * 256 + threadIdx.x;
  float M0 = -INFINITY, S0 = 0.f, M1 = -INFINITY, S1 = 0.f;
  for (int i = 0; i < NVT; ++i) {
    float2 p = P0[(size_t)i * kTok + t];
    if (p.x > M0) { S0 = S0 * __expf(M0 - p.x) + p.y; M0 = p.x; }
    else          { S0 += p.y * __expf(p.x - M0); }
  }
  for (int i = 0; i < NVT; ++i) {
    float2 p = P1[(size_t)i * kTok + t];
    if (p.x > M1) { S1 = S1 * __expf(M1 - p.x) + p.y; M1 = p.x; }
    else          { S1 += p.y * __expf(p.x - M1); }
  }
  float lse0  = M0 + logf(S0);
  float lse1  = M1 + logf(S1);
  float logp  = sel0[t] - lse0;
  float rlogp = sel1[t] - lse1;
  float d  = rlogp - logp;
  float kl = __expf(d) - d - 1.f;
  // coef_1 = exp(logp - stopgrad(logp)) == 1, clip == 1 -> loss = -adv + beta*kl
  float a  = adv[t >> 10];
  float mv = (float)mask[t];
  float loss = (-a + 0.1f * kl) * mv;

#pragma unroll
  for (int st = 32; st; st >>= 1) {
    loss += __shfl_xor(loss, st, 64);
    mv   += __shfl_xor(mv, st, 64);
  }
  __shared__ float lsum[4], msum[4];
  const int wave = threadIdx.x >> 6, lane = threadIdx.x & 63;
  if (lane == 0) { lsum[wave] = loss; msum[wave] = mv; }
  __syncthreads();
  if (threadIdx.x == 0) {
    atomicAdd(&accum[0], lsum[0] + lsum[1] + lsum[2] + lsum[3]);
    atomicAdd(&accum[1], msum[0] + msum[1] + msum[2] + msum[3]);
  }
}

__global__ void scalar_kernel(const float* __restrict__ accum, float* __restrict__ out)
{
  out[0] = accum[0] / fmaxf(accum[1], 1.f);
}

extern "C" void kernel_launch(void* const* d_in, const int* in_sizes, int n_in,
                              void* d_out, int out_size, void* d_ws, size_t ws_size,
                              hipStream_t stream)
{
  const float* x    = (const float*)d_in[0];
  const float* w    = (const float*)d_in[1];
  const float* rx   = (const float*)d_in[2];
  const float* rw   = (const float*)d_in[3];
  const float* adv  = (const float*)d_in[4];
  const int*   ids  = (const int*)d_in[5];
  const int*   mask = (const int*)d_in[6];
  float* out = (float*)d_out;

  // Workspace layout (~160 MB): f16 copies + partials + sel + accum.
  char* ws = (char*)d_ws;
  _Float16* Xh  = (_Float16*)ws;                         // 8 MB
  _Float16* Wh  = Xh + (size_t)kTok * kH;                // 64 MB
  _Float16* RXh = Wh + (size_t)kV * kH;                  // 8 MB
  _Float16* RWh = RXh + (size_t)kTok * kH;               // 64 MB
  float2*   P0  = (float2*)(RWh + (size_t)kV * kH);      // 8 MB
  float2*   P1  = P0 + (size_t)NVT * kTok;               // 8 MB
  float*    sel0 = (float*)(P1 + (size_t)NVT * kTok);
  float*    sel1 = sel0 + kTok;
  float*    accum = sel1 + kTok;

  hipMemsetAsync(accum, 0, 2 * sizeof(float), stream);

  convert_kernel<<<kTok * 128 / 256, 256, 0, stream>>>(x,  Xh);
  convert_kernel<<<kV   * 128 / 256, 256, 0, stream>>>(w,  Wh);
  convert_kernel<<<kTok * 128 / 256, 256, 0, stream>>>(rx, RXh);
  convert_kernel<<<kV   * 128 / 256, 256, 0, stream>>>(rw, RWh);

  sel_kernel<<<dim3(kTok / 4, 2), 256, 0, stream>>>(x, w, rx, rw, ids, sel0, sel1);

  lse_gemm_kernel<<<dim3(NMT, NVT, 2), 256, 0, stream>>>(Xh, Wh, RXh, RWh, P0, P1);

  finalize_kernel<<<kTok / 256, 256, 0, stream>>>(P0, P1, sel0, sel1, adv, mask, accum);
  scalar_kernel<<<1, 1, 0, stream>>>(accum, out);
}